// Round 9
// baseline (135.520 us; speedup 1.0000x reference)
//
#include <hip/hip_runtime.h>
#include <hip/hip_bf16.h>

#define EPS 1e-6f

typedef float  f32x4  __attribute__((ext_vector_type(4)));
typedef __bf16 bf16x8 __attribute__((ext_vector_type(8)));

// ---------- helpers ----------
static __device__ __forceinline__ unsigned short f2bf(float f) {
    unsigned int x = __float_as_uint(f);
    unsigned int r = (x + 0x7FFFu + ((x >> 16) & 1u)) >> 16;   // RNE
    return (unsigned short)r;
}
static __device__ __forceinline__ float bf2f(unsigned short u) {
    return __uint_as_float((unsigned int)u << 16);
}

// ---------- kernel 1: row stats (fp32) + bf16 conversion, both matrices ----------
__global__ __launch_bounds__(256) void prep_kernel(
    const float* __restrict__ protos, const float* __restrict__ querys,
    unsigned short* __restrict__ pb, unsigned short* __restrict__ qb,
    float* __restrict__ p_sq, float* __restrict__ p_sum,
    float* __restrict__ q_sq, float* __restrict__ q_sum)
{
    const int b   = blockIdx.x;
    const int tid = threadIdx.x;
    const float* src; unsigned short* dst; float* rsq; float* rsum;
    if (b < 1024) {
        src = protos + (size_t)b * 1024; dst = pb + (size_t)b * 1024;
        rsq = p_sq + b; rsum = p_sum + b;
    } else {
        const int r = b - 1024;
        src = querys + (size_t)r * 1024; dst = qb + (size_t)r * 1024;
        rsq = q_sq + r; rsum = q_sum + r;
    }

    const float4 v = reinterpret_cast<const float4*>(src)[tid];
    float s  = v.x + v.y + v.z + v.w;
    float ss = v.x * v.x + v.y * v.y + v.z * v.z + v.w * v.w;

    ushort4 o;
    o.x = f2bf(v.x); o.y = f2bf(v.y); o.z = f2bf(v.z); o.w = f2bf(v.w);
    reinterpret_cast<ushort4*>(dst)[tid] = o;

    #pragma unroll
    for (int m = 32; m >= 1; m >>= 1) {
        s  += __shfl_xor(s, m, 64);
        ss += __shfl_xor(ss, m, 64);
    }
    __shared__ float red[8];
    const int wave = tid >> 6;
    if ((tid & 63) == 0) { red[wave] = s; red[4 + wave] = ss; }
    __syncthreads();
    if (tid == 0) {
        *rsum = red[0] + red[1] + red[2] + red[3];
        *rsq  = red[4] + red[5] + red[6] + red[7];
    }
}

// ---------- kernel 2: bf16 MFMA GEMM + dist/exp epilogue ----------
// Tile 128(M)x64(N), BK=32, 256 threads = 4 waves (2x2), wave-tile 64x32 (4x2 frags).
// grid = 64x16 = 1024 blocks = 4 blocks/CU (R7's proven occupancy config).
// DOUBLE-BUFFERED LDS (2 x 12 KiB) + T3-minimum 2-phase: STAGE(next) issued BEFORE
// ds_read+MFMA(cur), single barrier per K-step -> load latency hides under compute
// and under 3 co-resident blocks.
// Bank-conflict swizzle (proven R7, rule #21): linear global_load_lds dest + global
// source chunk cs ^ ((row>>1)&3) + same XOR on ds_read chunk index.
__global__ __launch_bounds__(256, 4) void gemm_exp_kernel(
    const unsigned short* __restrict__ qb,   // [8192][1024] bf16 bits
    const unsigned short* __restrict__ pb,   // [1024][1024] bf16 bits
    const float* __restrict__ q_sq, const float* __restrict__ q_sum,
    const float* __restrict__ p_sq, const float* __restrict__ p_sum,
    unsigned short* __restrict__ e_out,      // [8192][1024] bf16 un-normalized exp(-dist)
    float* __restrict__ row_s, float* __restrict__ row_t,
    unsigned int* __restrict__ row_m)
{
    __shared__ unsigned short As[2][128 * 32];  // 2 x 8 KiB
    __shared__ unsigned short Bs[2][64 * 32];   // 2 x 4 KiB

    const int tid  = threadIdx.x;
    const int lane = tid & 63;
    const int wave = tid >> 6;
    const int wr = wave >> 1, wc = wave & 1;   // 2x2 waves: M-half, N-half
    const int l15 = lane & 15;
    const int l4  = lane >> 4;

    // XCD-aware bijective remap (1024 blocks, 8 XCDs; 1024%8==0)
    const int hwid  = blockIdx.x + blockIdx.y * 64;
    const int newid = (hwid & 7) * 128 + (hwid >> 3);
    const int bx = newid >> 4;    // row-block  0..63  (128 rows each)
    const int by = newid & 15;    // col-block  0..15  (64 cols each)

    f32x4 acc[4][2];
    #pragma unroll
    for (int m = 0; m < 4; ++m)
        #pragma unroll
        for (int n = 0; n < 2; ++n)
            acc[m][n] = (f32x4)0.0f;

    const size_t qbase = (size_t)(bx * 128) * 1024;
    const size_t pbase = (size_t)(by * 64) * 1024;

    // stage one K-step (A: 512 chunks of 16B, B: 256 chunks) into buffer BUF.
    // chunk lin -> row = lin>>2, dest chunk cs = lin&3 (LINEAR dest for gload_lds);
    // global source chunk = cs ^ ((row>>1)&3)  [involution; ds_read applies same XOR]
#define STAGE(BUF, KK) do {                                                              \
    const int la0 = tid, la1 = tid + 256, lb = tid;                                      \
    const int kpa0 = (la0 & 3) ^ ((la0 >> 3) & 3);                                       \
    const int kpa1 = (la1 & 3) ^ ((la1 >> 3) & 3);                                       \
    const int kpb  = (lb  & 3) ^ ((lb  >> 3) & 3);                                       \
    const unsigned short* ga0 = qb + qbase + (size_t)(la0 >> 2) * 1024 + (KK) + kpa0 * 8;\
    const unsigned short* ga1 = qb + qbase + (size_t)(la1 >> 2) * 1024 + (KK) + kpa1 * 8;\
    const unsigned short* gb  = pb + pbase + (size_t)(lb  >> 2) * 1024 + (KK) + kpb  * 8;\
    __builtin_amdgcn_global_load_lds((const __attribute__((address_space(1))) void*)ga0, \
        (__attribute__((address_space(3))) void*)(&As[BUF][la0 * 8]), 16, 0, 0);         \
    __builtin_amdgcn_global_load_lds((const __attribute__((address_space(1))) void*)ga1, \
        (__attribute__((address_space(3))) void*)(&As[BUF][la1 * 8]), 16, 0, 0);         \
    __builtin_amdgcn_global_load_lds((const __attribute__((address_space(1))) void*)gb,  \
        (__attribute__((address_space(3))) void*)(&Bs[BUF][lb * 8]), 16, 0, 0);          \
} while (0)

    // prologue
    STAGE(0, 0);
    __syncthreads();            // drain vmcnt(0): buffer 0 ready

    int cur = 0;
    #pragma unroll 1
    for (int kk = 0; kk < 1024; kk += 32) {
        if (kk < 992)
            STAGE(cur ^ 1, kk + 32);     // issue next-tile loads FIRST (2-phase overlap)

        bf16x8 a[4], b[2];
        #pragma unroll
        for (int m = 0; m < 4; ++m) {
            const int rowA = wr * 64 + m * 16 + l15;
            a[m] = *reinterpret_cast<const bf16x8*>(&As[cur][rowA * 32 + (l4 ^ ((rowA >> 1) & 3)) * 8]);
        }
        #pragma unroll
        for (int n = 0; n < 2; ++n) {
            const int rowB = wc * 32 + n * 16 + l15;
            b[n] = *reinterpret_cast<const bf16x8*>(&Bs[cur][rowB * 32 + (l4 ^ ((rowB >> 1) & 3)) * 8]);
        }
        #pragma unroll
        for (int m = 0; m < 4; ++m)
            #pragma unroll
            for (int n = 0; n < 2; ++n)
                acc[m][n] = __builtin_amdgcn_mfma_f32_16x16x32_bf16(a[m], b[n], acc[m][n], 0, 0, 0);

        __syncthreads();        // drains vmcnt (prefetch) + lgkm once per K-step
        cur ^= 1;
    }
#undef STAGE

    // ---- epilogue: dist -> e = exp(-dist); write e (bf16); per-row partials ----
    const int row0 = bx * 128 + wr * 64;          // + m*16 + l4*4 + r
    const int col0 = by * 64 + wc * 32;           // + n*16 + l15

    float ps[2], pm[2];
    #pragma unroll
    for (int n = 0; n < 2; ++n) {
        const int c = col0 + n * 16 + l15;
        ps[n] = p_sq[c];
        pm[n] = p_sum[c];
    }
    const float dee = 1024.0f * EPS * EPS;

    #pragma unroll
    for (int m = 0; m < 4; ++m) {
        #pragma unroll
        for (int r = 0; r < 4; ++r) {
            const int row = row0 + m * 16 + l4 * 4 + r;
            const float qs = q_sq[row], qm = q_sum[row];
            float se = 0.0f, te = 0.0f, mx = 0.0f;
            #pragma unroll
            for (int n = 0; n < 2; ++n) {
                const float cross = acc[m][n][r];
                const float sq = qs + ps[n] - 2.0f * cross + 2.0f * EPS * (qm - pm[n]) + dee;
                const float dist = sqrtf(fmaxf(sq, 0.0f));
                const float e = __expf(-dist);
                e_out[(size_t)row * 1024 + (col0 + n * 16 + l15)] = f2bf(e);
                se += e;
                te += e * dist;
                mx = fmaxf(mx, e);
            }
            #pragma unroll
            for (int msk = 8; msk >= 1; msk >>= 1) {   // reduce over the 16-lane col group
                se += __shfl_xor(se, msk, 64);
                te += __shfl_xor(te, msk, 64);
                mx = fmaxf(mx, __shfl_xor(mx, msk, 64));
            }
            if (l15 == 0) {
                atomicAdd(&row_s[row], se);
                atomicAdd(&row_t[row], te);
                atomicMax(&row_m[row], __float_as_uint(mx));
            }
        }
    }
}

// ---------- kernel 3: merged finalize + normalize ----------
__global__ __launch_bounds__(256) void normfin_kernel(
    const unsigned short* __restrict__ e16,
    const float* __restrict__ row_s, const float* __restrict__ row_t,
    const unsigned int* __restrict__ row_m,
    float* __restrict__ post, float* __restrict__ c_out, float* __restrict__ h_out)
{
    const int row = blockIdx.x;
    const int tid = threadIdx.x;
    const float s   = row_s[row];
    const float inv = 1.0f / s;
    if (tid == 0) {
        c_out[row] = __uint_as_float(row_m[row]) * inv;
        h_out[row] = logf(s) + row_t[row] * inv;   // h = t/s + log s
    }
    const ushort4 ev = reinterpret_cast<const ushort4*>(e16 + (size_t)row * 1024)[tid];
    float4 o;
    o.x = bf2f(ev.x) * inv;
    o.y = bf2f(ev.y) * inv;
    o.z = bf2f(ev.z) * inv;
    o.w = bf2f(ev.w) * inv;
    reinterpret_cast<float4*>(post + (size_t)row * 1024)[tid] = o;
}

// ---------- launcher ----------
extern "C" void kernel_launch(void* const* d_in, const int* in_sizes, int n_in,
                              void* d_out, int out_size, void* d_ws, size_t ws_size,
                              hipStream_t stream) {
    const float* protos = (const float*)d_in[0];  // [1024,1024]
    const float* querys = (const float*)d_in[1];  // [8192,1024]

    float* out   = (float*)d_out;
    float* post  = out;                            // 8192*1024
    float* c_out = out + (size_t)8192 * 1024;      // 8192
    float* h_out = c_out + 8192;                   // 8192

    char* ws = (char*)d_ws;
    unsigned short* qb  = (unsigned short*)ws;  ws += (size_t)8192 * 1024 * 2;
    unsigned short* pb  = (unsigned short*)ws;  ws += (size_t)1024 * 1024 * 2;
    unsigned short* e16 = (unsigned short*)ws;  ws += (size_t)8192 * 1024 * 2;
    float* q_sq  = (float*)ws;  ws += 8192 * 4;
    float* q_sum = (float*)ws;  ws += 8192 * 4;
    float* p_sq  = (float*)ws;  ws += 1024 * 4;
    float* p_sum = (float*)ws;  ws += 1024 * 4;
    float* row_s = (float*)ws;  ws += 8192 * 4;
    float* row_t = (float*)ws;  ws += 8192 * 4;
    unsigned int* row_m = (unsigned int*)ws;  ws += 8192 * 4;

    // zero the atomic accumulators (row_s, row_t, row_m are contiguous)
    (void)hipMemsetAsync(row_s, 0, 3 * 8192 * sizeof(float), stream);

    prep_kernel<<<9216, 256, 0, stream>>>(protos, querys, pb, qb, p_sq, p_sum, q_sq, q_sum);
    gemm_exp_kernel<<<dim3(64, 16), 256, 0, stream>>>(qb, pb, q_sq, q_sum, p_sq, p_sum,
                                                      e16, row_s, row_t, row_m);
    normfin_kernel<<<8192, 256, 0, stream>>>(e16, row_s, row_t, row_m, post, c_out, h_out);
}

// Round 10
// 133.598 us; speedup vs baseline: 1.0144x; 1.0144x over previous
//
#include <hip/hip_runtime.h>
#include <hip/hip_bf16.h>

#define EPS 1e-6f

typedef float  f32x4  __attribute__((ext_vector_type(4)));
typedef __bf16 bf16x8 __attribute__((ext_vector_type(8)));

// ---------- helpers ----------
static __device__ __forceinline__ unsigned short f2bf(float f) {
    unsigned int x = __float_as_uint(f);
    unsigned int r = (x + 0x7FFFu + ((x >> 16) & 1u)) >> 16;   // RNE
    return (unsigned short)r;
}
static __device__ __forceinline__ float bf2f(unsigned short u) {
    return __uint_as_float((unsigned int)u << 16);
}

// ---------- kernel 1: row stats (fp32) + bf16 conversion, both matrices ----------
__global__ __launch_bounds__(256) void prep_kernel(
    const float* __restrict__ protos, const float* __restrict__ querys,
    unsigned short* __restrict__ pb, unsigned short* __restrict__ qb,
    float* __restrict__ p_sq, float* __restrict__ p_sum,
    float* __restrict__ q_sq, float* __restrict__ q_sum)
{
    const int b   = blockIdx.x;
    const int tid = threadIdx.x;
    const float* src; unsigned short* dst; float* rsq; float* rsum;
    if (b < 1024) {
        src = protos + (size_t)b * 1024; dst = pb + (size_t)b * 1024;
        rsq = p_sq + b; rsum = p_sum + b;
    } else {
        const int r = b - 1024;
        src = querys + (size_t)r * 1024; dst = qb + (size_t)r * 1024;
        rsq = q_sq + r; rsum = q_sum + r;
    }

    const float4 v = reinterpret_cast<const float4*>(src)[tid];
    float s  = v.x + v.y + v.z + v.w;
    float ss = v.x * v.x + v.y * v.y + v.z * v.z + v.w * v.w;

    ushort4 o;
    o.x = f2bf(v.x); o.y = f2bf(v.y); o.z = f2bf(v.z); o.w = f2bf(v.w);
    reinterpret_cast<ushort4*>(dst)[tid] = o;

    #pragma unroll
    for (int m = 32; m >= 1; m >>= 1) {
        s  += __shfl_xor(s, m, 64);
        ss += __shfl_xor(ss, m, 64);
    }
    __shared__ float red[8];
    const int wave = tid >> 6;
    if ((tid & 63) == 0) { red[wave] = s; red[4 + wave] = ss; }
    __syncthreads();
    if (tid == 0) {
        *rsum = red[0] + red[1] + red[2] + red[3];
        *rsq  = red[4] + red[5] + red[6] + red[7];
    }
}

// ---------- kernel 2: bf16 MFMA GEMM + dist/exp epilogue ----------
// Tile 128x128, BK=32, 256 threads = 4 waves (2x2), wave-tile 64x64 (4x4 frags).
// grid = 64x8 = 512 blocks = 2 blocks/CU (64 KiB LDS).
// T4 counted-vmcnt depth-2 pipeline, 4-buffer LDS ring:
//   iter i: STAGE(buf[(i+2)&3]) ; s_waitcnt vmcnt(8) ; s_barrier ; compute(buf[i&3])
//   - vmcnt(8): 4 loads/stage x 2 newest stages stay in flight; oldest (buf[i]) drained.
//   - each wave drains ITS OWN buf[i] loads pre-barrier -> post-barrier buf[i] complete.
//   - STAGE(i+2) overwrites buf[(i-2)&3]: its reads finished before barrier(i-1),
//     which all waves passed before any STAGE(i+2) issue -> no WAR race (needs 4 bufs).
// Bank-conflict swizzle (proven R7/R9): linear gload_lds dest, source chunk
// cs ^ ((row>>1)&3), ds_read applies the same XOR. XCD remap: each XCD = P(2MB)+Q(2MB).
__global__ __launch_bounds__(256, 2) void gemm_exp_kernel(
    const unsigned short* __restrict__ qb,   // [8192][1024] bf16 bits
    const unsigned short* __restrict__ pb,   // [1024][1024] bf16 bits
    const float* __restrict__ q_sq, const float* __restrict__ q_sum,
    const float* __restrict__ p_sq, const float* __restrict__ p_sum,
    unsigned short* __restrict__ e_out,      // [8192][1024] bf16 un-normalized exp(-dist)
    float* __restrict__ row_s, float* __restrict__ row_t,
    unsigned int* __restrict__ row_m)
{
    __shared__ unsigned short As[4][128 * 32];  // 4 x 8 KiB
    __shared__ unsigned short Bs[4][128 * 32];  // 4 x 8 KiB

    const int tid  = threadIdx.x;
    const int lane = tid & 63;
    const int wave = tid >> 6;
    const int wr = wave >> 1, wc = wave & 1;
    const int l15 = lane & 15;
    const int l4  = lane >> 4;

    // XCD-aware bijective remap (512 blocks, 8 XCDs; 512%8==0)
    const int hwid  = blockIdx.x + blockIdx.y * 64;
    const int newid = (hwid & 7) * 64 + (hwid >> 3);
    const int bx = newid >> 3;    // row-block 0..63 (128 rows)
    const int by = newid & 7;     // col-block 0..7  (128 cols)

    f32x4 acc[4][4];
    #pragma unroll
    for (int m = 0; m < 4; ++m)
        #pragma unroll
        for (int n = 0; n < 4; ++n)
            acc[m][n] = (f32x4)0.0f;

    const size_t qbase = (size_t)(bx * 128) * 1024;
    const size_t pbase = (size_t)(by * 128) * 1024;

    // stage K-step KK into ring buffer BUF: A,B each 512 chunks of 16B; 4 loads/thread.
    // chunk lin: row = lin>>2, dest chunk cs = lin&3 (LINEAR dest for gload_lds);
    // global source chunk = cs ^ ((row>>1)&3) = (lin&3) ^ ((lin>>3)&3)
#define STAGE(BUF, KK) do {                                                              \
    const int la0 = tid, la1 = tid + 256;                                                \
    const int kp0 = (la0 & 3) ^ ((la0 >> 3) & 3);                                        \
    const int kp1 = (la1 & 3) ^ ((la1 >> 3) & 3);                                        \
    const unsigned short* ga0 = qb + qbase + (size_t)(la0 >> 2) * 1024 + (KK) + kp0 * 8; \
    const unsigned short* ga1 = qb + qbase + (size_t)(la1 >> 2) * 1024 + (KK) + kp1 * 8; \
    const unsigned short* gb0 = pb + pbase + (size_t)(la0 >> 2) * 1024 + (KK) + kp0 * 8; \
    const unsigned short* gb1 = pb + pbase + (size_t)(la1 >> 2) * 1024 + (KK) + kp1 * 8; \
    __builtin_amdgcn_global_load_lds((const __attribute__((address_space(1))) void*)ga0, \
        (__attribute__((address_space(3))) void*)(&As[BUF][la0 * 8]), 16, 0, 0);         \
    __builtin_amdgcn_global_load_lds((const __attribute__((address_space(1))) void*)ga1, \
        (__attribute__((address_space(3))) void*)(&As[BUF][la1 * 8]), 16, 0, 0);         \
    __builtin_amdgcn_global_load_lds((const __attribute__((address_space(1))) void*)gb0, \
        (__attribute__((address_space(3))) void*)(&Bs[BUF][la0 * 8]), 16, 0, 0);         \
    __builtin_amdgcn_global_load_lds((const __attribute__((address_space(1))) void*)gb1, \
        (__attribute__((address_space(3))) void*)(&Bs[BUF][la1 * 8]), 16, 0, 0);         \
} while (0)

#define COMPUTE(BUF) do {                                                                \
    bf16x8 a[4], b[4];                                                                   \
    _Pragma("unroll")                                                                    \
    for (int m = 0; m < 4; ++m) {                                                        \
        const int rowA = wr * 64 + m * 16 + l15;                                         \
        a[m] = *reinterpret_cast<const bf16x8*>(                                         \
            &As[BUF][rowA * 32 + (l4 ^ ((rowA >> 1) & 3)) * 8]);                         \
    }                                                                                    \
    _Pragma("unroll")                                                                    \
    for (int n = 0; n < 4; ++n) {                                                        \
        const int rowB = wc * 64 + n * 16 + l15;                                         \
        b[n] = *reinterpret_cast<const bf16x8*>(                                         \
            &Bs[BUF][rowB * 32 + (l4 ^ ((rowB >> 1) & 3)) * 8]);                         \
    }                                                                                    \
    _Pragma("unroll")                                                                    \
    for (int m = 0; m < 4; ++m)                                                          \
        _Pragma("unroll")                                                                \
        for (int n = 0; n < 4; ++n)                                                      \
            acc[m][n] = __builtin_amdgcn_mfma_f32_16x16x32_bf16(a[m], b[n], acc[m][n], 0, 0, 0); \
} while (0)

    // prologue: two stages in flight
    STAGE(0, 0);
    STAGE(1, 32);

    #pragma unroll 1
    for (int i = 0; i < 30; ++i) {
        STAGE((i + 2) & 3, (i + 2) * 32);
        asm volatile("s_waitcnt vmcnt(8)" ::: "memory");   // oldest stage (buf i) drained
        __builtin_amdgcn_s_barrier();
        __builtin_amdgcn_sched_barrier(0);
        COMPUTE(i & 3);
    }
    // tail i=30: stages 30,31 in flight (8 loads) -> drain stage 30
    asm volatile("s_waitcnt vmcnt(4)" ::: "memory");
    __builtin_amdgcn_s_barrier();
    __builtin_amdgcn_sched_barrier(0);
    COMPUTE(2);
    // tail i=31
    asm volatile("s_waitcnt vmcnt(0)" ::: "memory");
    __builtin_amdgcn_s_barrier();
    __builtin_amdgcn_sched_barrier(0);
    COMPUTE(3);

#undef STAGE
#undef COMPUTE

    // ---- epilogue: dist -> e = exp(-dist); write e (bf16); per-row partials ----
    const int row0 = bx * 128 + wr * 64;          // + m*16 + l4*4 + r
    const int col0 = by * 128 + wc * 64;          // + n*16 + l15

    float ps[4], pm[4];
    #pragma unroll
    for (int n = 0; n < 4; ++n) {
        const int c = col0 + n * 16 + l15;
        ps[n] = p_sq[c];
        pm[n] = p_sum[c];
    }
    const float dee = 1024.0f * EPS * EPS;

    #pragma unroll
    for (int m = 0; m < 4; ++m) {
        #pragma unroll
        for (int r = 0; r < 4; ++r) {
            const int row = row0 + m * 16 + l4 * 4 + r;
            const float qs = q_sq[row], qm = q_sum[row];
            float se = 0.0f, te = 0.0f, mx = 0.0f;
            #pragma unroll
            for (int n = 0; n < 4; ++n) {
                const float cross = acc[m][n][r];
                const float sq = qs + ps[n] - 2.0f * cross + 2.0f * EPS * (qm - pm[n]) + dee;
                const float dist = sqrtf(fmaxf(sq, 0.0f));
                const float e = __expf(-dist);
                e_out[(size_t)row * 1024 + (col0 + n * 16 + l15)] = f2bf(e);
                se += e;
                te += e * dist;
                mx = fmaxf(mx, e);
            }
            #pragma unroll
            for (int msk = 8; msk >= 1; msk >>= 1) {   // reduce over the 16-lane col group
                se += __shfl_xor(se, msk, 64);
                te += __shfl_xor(te, msk, 64);
                mx = fmaxf(mx, __shfl_xor(mx, msk, 64));
            }
            if (l15 == 0) {
                atomicAdd(&row_s[row], se);
                atomicAdd(&row_t[row], te);
                atomicMax(&row_m[row], __float_as_uint(mx));
            }
        }
    }
}

// ---------- kernel 3: merged finalize + normalize ----------
__global__ __launch_bounds__(256) void normfin_kernel(
    const unsigned short* __restrict__ e16,
    const float* __restrict__ row_s, const float* __restrict__ row_t,
    const unsigned int* __restrict__ row_m,
    float* __restrict__ post, float* __restrict__ c_out, float* __restrict__ h_out)
{
    const int row = blockIdx.x;
    const int tid = threadIdx.x;
    const float s   = row_s[row];
    const float inv = 1.0f / s;
    if (tid == 0) {
        c_out[row] = __uint_as_float(row_m[row]) * inv;
        h_out[row] = logf(s) + row_t[row] * inv;   // h = t/s + log s
    }
    const ushort4 ev = reinterpret_cast<const ushort4*>(e16 + (size_t)row * 1024)[tid];
    float4 o;
    o.x = bf2f(ev.x) * inv;
    o.y = bf2f(ev.y) * inv;
    o.z = bf2f(ev.z) * inv;
    o.w = bf2f(ev.w) * inv;
    reinterpret_cast<float4*>(post + (size_t)row * 1024)[tid] = o;
}

// ---------- launcher ----------
extern "C" void kernel_launch(void* const* d_in, const int* in_sizes, int n_in,
                              void* d_out, int out_size, void* d_ws, size_t ws_size,
                              hipStream_t stream) {
    const float* protos = (const float*)d_in[0];  // [1024,1024]
    const float* querys = (const float*)d_in[1];  // [8192,1024]

    float* out   = (float*)d_out;
    float* post  = out;                            // 8192*1024
    float* c_out = out + (size_t)8192 * 1024;      // 8192
    float* h_out = c_out + 8192;                   // 8192

    char* ws = (char*)d_ws;
    unsigned short* qb  = (unsigned short*)ws;  ws += (size_t)8192 * 1024 * 2;
    unsigned short* pb  = (unsigned short*)ws;  ws += (size_t)1024 * 1024 * 2;
    unsigned short* e16 = (unsigned short*)ws;  ws += (size_t)8192 * 1024 * 2;
    float* q_sq  = (float*)ws;  ws += 8192 * 4;
    float* q_sum = (float*)ws;  ws += 8192 * 4;
    float* p_sq  = (float*)ws;  ws += 1024 * 4;
    float* p_sum = (float*)ws;  ws += 1024 * 4;
    float* row_s = (float*)ws;  ws += 8192 * 4;
    float* row_t = (float*)ws;  ws += 8192 * 4;
    unsigned int* row_m = (unsigned int*)ws;  ws += 8192 * 4;

    // zero the atomic accumulators (row_s, row_t, row_m are contiguous)
    (void)hipMemsetAsync(row_s, 0, 3 * 8192 * sizeof(float), stream);

    prep_kernel<<<9216, 256, 0, stream>>>(protos, querys, pb, qb, p_sq, p_sum, q_sq, q_sum);
    gemm_exp_kernel<<<dim3(64, 8), 256, 0, stream>>>(qb, pb, q_sq, q_sum, p_sq, p_sum,
                                                     e16, row_s, row_t, row_m);
    normfin_kernel<<<8192, 256, 0, stream>>>(e16, row_s, row_t, row_m, post, c_out, h_out);
}